// Round 8
// baseline (494.613 us; speedup 1.0000x reference)
//
#include <hip/hip_runtime.h>
#include <hip/hip_bf16.h>

#define B_SZ 4
#define T_SEQ 2048
#define NH 16
#define DK 64
#define DM 1024

typedef __bf16 bf16x8 __attribute__((ext_vector_type(8)));
typedef __bf16 bf16x4 __attribute__((ext_vector_type(4)));
typedef float floatx4 __attribute__((ext_vector_type(4)));

__device__ __forceinline__ void gl2lds16(const __bf16* g, __bf16* l) {
    __builtin_amdgcn_global_load_lds(
        (const __attribute__((address_space(1))) unsigned int*)g,
        (__attribute__((address_space(3))) unsigned int*)l, 16, 0, 0);
}

// fp32 -> bf16, vectorized x4
__global__ __launch_bounds__(256) void convert4_kernel(const float* __restrict__ src,
                                                       __hip_bfloat16* __restrict__ dst,
                                                       int n4)
{
    const int i = blockIdx.x * 256 + threadIdx.x;
    if (i >= n4) return;
    const float4 v = ((const float4*)src)[i];
    bf16x4 e = { (__bf16)v.x, (__bf16)v.y, (__bf16)v.z, (__bf16)v.w };
    *(bf16x4*)&dst[i * 4] = e;
}

// all four weight matrices (contiguous dst), vectorized x4
__global__ __launch_bounds__(256) void convertw_kernel(const float* __restrict__ w0,
                                                       const float* __restrict__ w1,
                                                       const float* __restrict__ w2,
                                                       const float* __restrict__ w3,
                                                       __hip_bfloat16* __restrict__ dst)
{
    const int i = blockIdx.x * 256 + threadIdx.x;      // 1M threads
    const int seg = i >> 18;                            // 256K vec4 per weight
    const int off = i & 262143;
    const float* src = (seg == 0) ? w0 : (seg == 1) ? w1 : (seg == 2) ? w2 : w3;
    const float4 v = ((const float4*)src)[off];
    bf16x4 e = { (__bf16)v.x, (__bf16)v.y, (__bf16)v.z, (__bf16)v.w };
    *(bf16x4*)&dst[i * 4] = e;
}

// ---------------------------------------------------------------------------
// m97-style 128x128 GEMM mainloop: C[m][n] = sum_k A[m][k]*W[n][k], K=1024.
// ---------------------------------------------------------------------------
__device__ __forceinline__ void gemm_mainloop(const __bf16* __restrict__ A,
                                              const __bf16* __restrict__ W,
                                              int m0, int n0,
                                              __bf16* As, __bf16* Bs,
                                              floatx4 acc[4][4])
{
    const int tid  = threadIdx.x;
    const int wv_  = tid >> 6;
    const int lane = tid & 63;
    const int l16  = lane & 15;
    const int quad = lane >> 4;

    const int srow = wv_ * 16 + (lane >> 2);
    const int scol = (lane & 3) * 8;
    const __bf16* ag = A + (size_t)(m0 + srow) * 1024 + scol;
    const __bf16* bg = W + (size_t)(n0 + srow) * 1024 + scol;
    __bf16* al = As + wv_ * 512;
    __bf16* bl = Bs + wv_ * 512;

    const int mi0 = (wv_ >> 1) * 64;
    const int ni0 = (wv_ & 1) * 64;

    for (int k0 = 0; k0 < 1024; k0 += 32) {
        __syncthreads();
        gl2lds16(ag + k0,             al);
        gl2lds16(ag + 64 * 1024 + k0, al + 2048);
        gl2lds16(bg + k0,             bl);
        gl2lds16(bg + 64 * 1024 + k0, bl + 2048);
        __syncthreads();

        bf16x8 af[4], bfr[4];
        #pragma unroll
        for (int i = 0; i < 4; ++i)
            af[i] = *(const bf16x8*)(As + (mi0 + i * 16 + l16) * 32 + quad * 8);
        #pragma unroll
        for (int j = 0; j < 4; ++j)
            bfr[j] = *(const bf16x8*)(Bs + (ni0 + j * 16 + l16) * 32 + quad * 8);
        #pragma unroll
        for (int i = 0; i < 4; ++i)
            #pragma unroll
            for (int j = 0; j < 4; ++j)
                acc[i][j] = __builtin_amdgcn_mfma_f32_16x16x32_bf16(af[i], bfr[j], acc[i][j], 0, 0, 0);
    }
}

// Fused QKV projection. grid (24, 64).
__global__ __launch_bounds__(256) void qkv_gemm_kernel(const __bf16* __restrict__ A,
                                                       const __bf16* __restrict__ Wq,
                                                       const __bf16* __restrict__ Wk,
                                                       const __bf16* __restrict__ Wv,
                                                       __hip_bfloat16* __restrict__ Q,
                                                       __hip_bfloat16* __restrict__ Kd,
                                                       __hip_bfloat16* __restrict__ VT)
{
    __shared__ __align__(16) __bf16 As[128 * 32];
    __shared__ __align__(16) __bf16 Bs[128 * 32];

    const int nt  = blockIdx.x;
    const int mt  = blockIdx.y;
    const int mat = nt >> 3;
    const int n0  = (nt & 7) * 128;
    const int m0  = mt * 128;
    const __bf16* W = (mat == 0) ? Wq : (mat == 1) ? Wk : Wv;

    floatx4 acc[4][4] = {};
    gemm_mainloop(A, W, m0, n0, As, Bs, acc);

    const int wv_  = threadIdx.x >> 6;
    const int lane = threadIdx.x & 63;
    const int l16  = lane & 15;
    const int quad = lane >> 4;
    const int mi0  = (wv_ >> 1) * 64;
    const int ni0  = (wv_ & 1) * 64;

    if (mat < 2) {
        __hip_bfloat16* dst = (mat == 0) ? Q : Kd;
        #pragma unroll
        for (int i = 0; i < 4; ++i) {
            #pragma unroll
            for (int j = 0; j < 4; ++j) {
                const int col = n0 + ni0 + j * 16 + l16;
                const int h = col >> 6, d = col & 63;
                #pragma unroll
                for (int r = 0; r < 4; ++r) {
                    const int row = m0 + mi0 + i * 16 + quad * 4 + r;
                    const int b = row >> 11, t = row & (T_SEQ - 1);
                    dst[(((size_t)(b * NH + h)) * T_SEQ + t) * DK + d] = __float2bfloat16(acc[i][j][r]);
                }
            }
        }
    } else {
        #pragma unroll
        for (int i = 0; i < 4; ++i) {
            const int row0 = m0 + mi0 + i * 16 + quad * 4;
            const int b = row0 >> 11, t0 = row0 & (T_SEQ - 1);
            #pragma unroll
            for (int j = 0; j < 4; ++j) {
                const int col = n0 + ni0 + j * 16 + l16;
                const int h = col >> 6, d = col & 63;
                bf16x4 e;
                #pragma unroll
                for (int r = 0; r < 4; ++r) e[r] = (__bf16)acc[i][j][r];
                *(bf16x4*)&VT[(((size_t)(b * NH + h)) * DK + d) * T_SEQ + t0] = e;
            }
        }
    }
}

// O projection -> fp32 d_out. grid (8, 64).
__global__ __launch_bounds__(256) void oproj_gemm_kernel(const __bf16* __restrict__ A,
                                                         const __bf16* __restrict__ W,
                                                         float* __restrict__ out)
{
    __shared__ __align__(16) __bf16 As[128 * 32];
    __shared__ __align__(16) __bf16 Bs[128 * 32];

    const int n0 = blockIdx.x * 128;
    const int m0 = blockIdx.y * 128;

    floatx4 acc[4][4] = {};
    gemm_mainloop(A, W, m0, n0, As, Bs, acc);

    const int wv_  = threadIdx.x >> 6;
    const int lane = threadIdx.x & 63;
    const int l16  = lane & 15;
    const int quad = lane >> 4;
    const int mi0  = (wv_ >> 1) * 64;
    const int ni0  = (wv_ & 1) * 64;

    #pragma unroll
    for (int i = 0; i < 4; ++i) {
        #pragma unroll
        for (int j = 0; j < 4; ++j) {
            const int col = n0 + ni0 + j * 16 + l16;
            #pragma unroll
            for (int r = 0; r < 4; ++r) {
                const int row = m0 + mi0 + i * 16 + quad * 4 + r;
                out[(size_t)row * DM + col] = acc[i][j][r];
            }
        }
    }
}

// In-place RoPE on Q and K. Q additionally scaled by 1/8.
__global__ __launch_bounds__(256) void rope_kernel(__hip_bfloat16* __restrict__ Q,
                                                   __hip_bfloat16* __restrict__ K,
                                                   const int* __restrict__ tp)
{
    const int idx = blockIdx.x * 256 + threadIdx.x;
    const int f = idx & 31;
    const int t = (idx >> 5) & (T_SEQ - 1);
    const int h = (idx >> 16) & (NH - 1);
    const int b = idx >> 20;

    const int pos = tp[b * T_SEQ + t];
    const float inv = exp2f(-(float)f * 0.41524101186092029f);
    const float ang = (float)pos * inv;
    float s, c;
    sincosf(ang, &s, &c);

    const size_t off = (((size_t)(b * NH + h)) * T_SEQ + t) * DK + 2 * f;
    const float q0 = __bfloat162float(Q[off]);
    const float q1 = __bfloat162float(Q[off + 1]);
    Q[off]     = __float2bfloat16((q0 * c - q1 * s) * 0.125f);
    Q[off + 1] = __float2bfloat16((q1 * c + q0 * s) * 0.125f);
    const float k0 = __bfloat162float(K[off]);
    const float k1 = __bfloat162float(K[off + 1]);
    K[off]     = __float2bfloat16(k0 * c - k1 * s);
    K[off + 1] = __float2bfloat16(k1 * c + k0 * s);
}

// ---------------------------------------------------------------------------
// Flash attention v3: block = one 64-row Q-supertile shared by 4 waves
// (wave wv owns rows qs0+wv*16). All waves read identical K/V addresses per
// chunk (L1 temporal reuse), kept lockstep by per-chunk __syncthreads
// (uniform trip count). Block processes supertile pair (st, 31-st): every
// block = 66 chunks -> zero taper. Grid 1024 = 4 blocks/CU.
// ---------------------------------------------------------------------------
__global__ __launch_bounds__(256) void fattn_kernel(const __bf16* __restrict__ Q,
                                                    const __bf16* __restrict__ K,
                                                    const __bf16* __restrict__ VT,
                                                    __hip_bfloat16* __restrict__ AO)
{
    __shared__ __align__(16) __hip_bfloat16 sh_p[4][16][40];

    const int wv   = threadIdx.x >> 6;
    const int lane = threadIdx.x & 63;
    const int l16  = lane & 15;
    const int quad = lane >> 4;

    const int bk = blockIdx.x;                  // 1024 blocks
    const int bh = bk >> 4;
    const int pr = bk & 15;
    const int b = bh >> 4, h = bh & (NH - 1);

    const __bf16* Kb = K  + (size_t)bh * T_SEQ * DK;
    const __bf16* Vb = VT + (size_t)bh * DK * T_SEQ;

    #pragma unroll 1
    for (int s = 0; s < 2; ++s) {
        const int st  = (s == 0) ? pr : 31 - pr;
        const int qs0 = st * 64;
        const int qi0 = qs0 + wv * 16;
        const int qi  = qi0 + l16;              // this lane's Q-row

        const __bf16* Qp = Q + ((size_t)bh * T_SEQ + qi0 + l16) * DK + quad * 8;
        const bf16x8 qb0 = *(const bf16x8*)Qp;
        const bf16x8 qb1 = *(const bf16x8*)(Qp + 32);

        floatx4 o0 = {0,0,0,0}, o1 = {0,0,0,0}, o2 = {0,0,0,0}, o3 = {0,0,0,0};
        float m_run = -1e30f;
        float l_run = 0.f;

        const int nch   = (qs0 + 95) >> 5;      // block-uniform chunk count
        const int myn   = (qi0 + 47) >> 5;      // this wave's active chunks
        const int nfull = (qi0 + 1) >> 5;       // chunks needing no mask

        const __bf16* kp0 = Kb + (size_t)l16 * DK + quad * 8;
        bf16x8 ka0l = *(const bf16x8*)(kp0);
        bf16x8 ka0h = *(const bf16x8*)(kp0 + 32);
        bf16x8 ka1l = *(const bf16x8*)(kp0 + 16 * DK);
        bf16x8 ka1h = *(const bf16x8*)(kp0 + 16 * DK + 32);

        for (int c = 0; c < nch; ++c) {
            __syncthreads();                    // lockstep (uniform trip count)
            if (c >= myn) continue;             // fully-masked for this wave

            const int tj0 = c * 32;

            floatx4 s0 = {0,0,0,0}, s1 = {0,0,0,0};
            s0 = __builtin_amdgcn_mfma_f32_16x16x32_bf16(ka0l, qb0, s0, 0, 0, 0);
            s0 = __builtin_amdgcn_mfma_f32_16x16x32_bf16(ka0h, qb1, s0, 0, 0, 0);
            s1 = __builtin_amdgcn_mfma_f32_16x16x32_bf16(ka1l, qb0, s1, 0, 0, 0);
            s1 = __builtin_amdgcn_mfma_f32_16x16x32_bf16(ka1h, qb1, s1, 0, 0, 0);

            {
                const int cn = (c + 1 < myn) ? c + 1 : c;
                const __bf16* kpn = Kb + ((size_t)(cn * 32) + l16) * DK + quad * 8;
                ka0l = *(const bf16x8*)(kpn);
                ka0h = *(const bf16x8*)(kpn + 32);
                ka1l = *(const bf16x8*)(kpn + 16 * DK);
                ka1h = *(const bf16x8*)(kpn + 16 * DK + 32);
            }

            const __bf16* vp = Vb + (size_t)l16 * T_SEQ + tj0 + quad * 8;
            const bf16x8 va0 = *(const bf16x8*)(vp);
            const bf16x8 va1 = *(const bf16x8*)(vp + 16 * T_SEQ);
            const bf16x8 va2 = *(const bf16x8*)(vp + 32 * T_SEQ);
            const bf16x8 va3 = *(const bf16x8*)(vp + 48 * T_SEQ);

            float v0[4], v1[4];
            if (c < nfull) {                    // wave-uniform: no masking needed
                #pragma unroll
                for (int r = 0; r < 4; ++r) { v0[r] = s0[r]; v1[r] = s1[r]; }
            } else {
                #pragma unroll
                for (int r = 0; r < 4; ++r) {
                    v0[r] = (tj0 + quad * 4 + r      <= qi) ? s0[r] : -1e30f;
                    v1[r] = (tj0 + 16 + quad * 4 + r <= qi) ? s1[r] : -1e30f;
                }
            }
            float mloc = -1e30f;
            #pragma unroll
            for (int r = 0; r < 4; ++r) mloc = fmaxf(mloc, fmaxf(v0[r], v1[r]));
            mloc = fmaxf(mloc, __shfl_xor(mloc, 16));
            mloc = fmaxf(mloc, __shfl_xor(mloc, 32));
            const float nm = fmaxf(m_run, mloc);
            const float al = __expf(m_run - nm);
            m_run = nm;

            float p0[4], p1[4];
            float ls = 0.f;
            #pragma unroll
            for (int r = 0; r < 4; ++r) {
                p0[r] = __expf(v0[r] - nm);
                p1[r] = __expf(v1[r] - nm);
                ls += p0[r] + p1[r];
            }
            ls += __shfl_xor(ls, 16);
            ls += __shfl_xor(ls, 32);
            l_run = l_run * al + ls;

            #pragma unroll
            for (int r = 0; r < 4; ++r) {
                o0[r] *= al; o1[r] *= al; o2[r] *= al; o3[r] *= al;
            }

            bf16x4 w0, w1;
            #pragma unroll
            for (int r = 0; r < 4; ++r) { w0[r] = (__bf16)p0[r]; w1[r] = (__bf16)p1[r]; }
            *(bf16x4*)&sh_p[wv][l16][quad * 4]      = w0;
            *(bf16x4*)&sh_p[wv][l16][16 + quad * 4] = w1;
            asm volatile("s_waitcnt lgkmcnt(0)" ::: "memory");
            __builtin_amdgcn_wave_barrier();

            const bf16x8 pb = *(const bf16x8*)&sh_p[wv][l16][quad * 8];

            o0 = __builtin_amdgcn_mfma_f32_16x16x32_bf16(va0, pb, o0, 0, 0, 0);
            o1 = __builtin_amdgcn_mfma_f32_16x16x32_bf16(va1, pb, o1, 0, 0, 0);
            o2 = __builtin_amdgcn_mfma_f32_16x16x32_bf16(va2, pb, o2, 0, 0, 0);
            o3 = __builtin_amdgcn_mfma_f32_16x16x32_bf16(va3, pb, o3, 0, 0, 0);
            __builtin_amdgcn_wave_barrier();
        }

        const float inv = 1.0f / l_run;
        __hip_bfloat16* Ao = AO + ((size_t)b * T_SEQ + qi0 + l16) * DM + h * 64 + quad * 4;
        bf16x4 e;
        #pragma unroll
        for (int r = 0; r < 4; ++r) e[r] = (__bf16)(o0[r] * inv);
        *(bf16x4*)(Ao +  0) = e;
        #pragma unroll
        for (int r = 0; r < 4; ++r) e[r] = (__bf16)(o1[r] * inv);
        *(bf16x4*)(Ao + 16) = e;
        #pragma unroll
        for (int r = 0; r < 4; ++r) e[r] = (__bf16)(o2[r] * inv);
        *(bf16x4*)(Ao + 32) = e;
        #pragma unroll
        for (int r = 0; r < 4; ++r) e[r] = (__bf16)(o3[r] * inv);
        *(bf16x4*)(Ao + 48) = e;
    }
}

extern "C" void kernel_launch(void* const* d_in, const int* in_sizes, int n_in,
                              void* d_out, int out_size, void* d_ws, size_t ws_size,
                              hipStream_t stream) {
    const float* x  = (const float*)d_in[0];
    const int*   tp = (const int*)d_in[1];
    const float* wq = (const float*)d_in[2];
    const float* wk = (const float*)d_in[3];
    const float* wv = (const float*)d_in[4];
    const float* wo = (const float*)d_in[5];

    char* ws = (char*)d_ws;
    const size_t XSZ = (size_t)B_SZ * T_SEQ * DM * 2;       // 16.78 MB
    const size_t WSZ = (size_t)DM * DM * 2;                 // 2 MB
    const size_t SZ  = (size_t)B_SZ * NH * T_SEQ * DK * 2;  // 16.78 MB

    __hip_bfloat16* xb  = (__hip_bfloat16*)(ws);
    __hip_bfloat16* wqb = (__hip_bfloat16*)(ws + XSZ);       // wq..wo contiguous
    __hip_bfloat16* wkb = (__hip_bfloat16*)(ws + XSZ + WSZ);
    __hip_bfloat16* wvb = (__hip_bfloat16*)(ws + XSZ + 2 * WSZ);
    __hip_bfloat16* wob = (__hip_bfloat16*)(ws + XSZ + 3 * WSZ);
    __hip_bfloat16* Q   = (__hip_bfloat16*)(ws + XSZ + 4 * WSZ);
    __hip_bfloat16* K   = (__hip_bfloat16*)(ws + XSZ + 4 * WSZ + SZ);
    __hip_bfloat16* VT  = (__hip_bfloat16*)(ws + XSZ + 4 * WSZ + 2 * SZ);
    __hip_bfloat16* AO  = (__hip_bfloat16*)(ws + XSZ + 4 * WSZ + 3 * SZ);
    float* out = (float*)d_out;

    // 1. canonicalize fp32 inputs to bf16 (x + all four weights)
    convert4_kernel<<<8192, 256, 0, stream>>>(x, xb, B_SZ * T_SEQ * DM / 4);
    convertw_kernel<<<4096, 256, 0, stream>>>(wq, wk, wv, wo, wqb);

    // 2. fused QKV projection: Q,K -> [bh][t][64]; V -> [bh][64][t]
    qkv_gemm_kernel<<<dim3(24, 64), 256, 0, stream>>>(
        (const __bf16*)xb, (const __bf16*)wqb, (const __bf16*)wkb, (const __bf16*)wvb,
        Q, K, VT);

    // 3. RoPE in place on Q (scaled by 1/8), K
    rope_kernel<<<16384, 256, 0, stream>>>(Q, K, tp);

    // 4. flash attention -> AO [B][T][DM] (bf16)
    fattn_kernel<<<1024, 256, 0, stream>>>((const __bf16*)Q, (const __bf16*)K,
                                           (const __bf16*)VT, AO);

    // 5. O projection -> d_out (fp32)
    oproj_gemm_kernel<<<dim3(8, 64), 256, 0, stream>>>(
        (const __bf16*)AO, (const __bf16*)wob, out);
}

// Round 9
// 450.652 us; speedup vs baseline: 1.0976x; 1.0976x over previous
//
#include <hip/hip_runtime.h>
#include <hip/hip_bf16.h>

#define B_SZ 4
#define T_SEQ 2048
#define NH 16
#define DK 64
#define DM 1024

typedef __bf16 bf16x8 __attribute__((ext_vector_type(8)));
typedef __bf16 bf16x4 __attribute__((ext_vector_type(4)));
typedef float floatx4 __attribute__((ext_vector_type(4)));

__device__ __forceinline__ void gl2lds16(const __bf16* g, __bf16* l) {
    __builtin_amdgcn_global_load_lds(
        (const __attribute__((address_space(1))) unsigned int*)g,
        (__attribute__((address_space(3))) unsigned int*)l, 16, 0, 0);
}

// fp32 -> bf16, vectorized x4
__global__ __launch_bounds__(256) void convert4_kernel(const float* __restrict__ src,
                                                       __hip_bfloat16* __restrict__ dst,
                                                       int n4)
{
    const int i = blockIdx.x * 256 + threadIdx.x;
    if (i >= n4) return;
    const float4 v = ((const float4*)src)[i];
    bf16x4 e = { (__bf16)v.x, (__bf16)v.y, (__bf16)v.z, (__bf16)v.w };
    *(bf16x4*)&dst[i * 4] = e;
}

// all four weight matrices (contiguous dst), vectorized x4
__global__ __launch_bounds__(256) void convertw_kernel(const float* __restrict__ w0,
                                                       const float* __restrict__ w1,
                                                       const float* __restrict__ w2,
                                                       const float* __restrict__ w3,
                                                       __hip_bfloat16* __restrict__ dst)
{
    const int i = blockIdx.x * 256 + threadIdx.x;      // 1M threads
    const int seg = i >> 18;                            // 256K vec4 per weight
    const int off = i & 262143;
    const float* src = (seg == 0) ? w0 : (seg == 1) ? w1 : (seg == 2) ? w2 : w3;
    const float4 v = ((const float4*)src)[off];
    bf16x4 e = { (__bf16)v.x, (__bf16)v.y, (__bf16)v.z, (__bf16)v.w };
    *(bf16x4*)&dst[i * 4] = e;
}

// ---------------------------------------------------------------------------
// m97-style 128x128 GEMM mainloop: C[m][n] = sum_k A[m][k]*W[n][k], K=1024.
// ---------------------------------------------------------------------------
__device__ __forceinline__ void gemm_mainloop(const __bf16* __restrict__ A,
                                              const __bf16* __restrict__ W,
                                              int m0, int n0,
                                              __bf16* As, __bf16* Bs,
                                              floatx4 acc[4][4])
{
    const int tid  = threadIdx.x;
    const int wv_  = tid >> 6;
    const int lane = tid & 63;
    const int l16  = lane & 15;
    const int quad = lane >> 4;

    const int srow = wv_ * 16 + (lane >> 2);
    const int scol = (lane & 3) * 8;
    const __bf16* ag = A + (size_t)(m0 + srow) * 1024 + scol;
    const __bf16* bg = W + (size_t)(n0 + srow) * 1024 + scol;
    __bf16* al = As + wv_ * 512;
    __bf16* bl = Bs + wv_ * 512;

    const int mi0 = (wv_ >> 1) * 64;
    const int ni0 = (wv_ & 1) * 64;

    for (int k0 = 0; k0 < 1024; k0 += 32) {
        __syncthreads();
        gl2lds16(ag + k0,             al);
        gl2lds16(ag + 64 * 1024 + k0, al + 2048);
        gl2lds16(bg + k0,             bl);
        gl2lds16(bg + 64 * 1024 + k0, bl + 2048);
        __syncthreads();

        bf16x8 af[4], bfr[4];
        #pragma unroll
        for (int i = 0; i < 4; ++i)
            af[i] = *(const bf16x8*)(As + (mi0 + i * 16 + l16) * 32 + quad * 8);
        #pragma unroll
        for (int j = 0; j < 4; ++j)
            bfr[j] = *(const bf16x8*)(Bs + (ni0 + j * 16 + l16) * 32 + quad * 8);
        #pragma unroll
        for (int i = 0; i < 4; ++i)
            #pragma unroll
            for (int j = 0; j < 4; ++j)
                acc[i][j] = __builtin_amdgcn_mfma_f32_16x16x32_bf16(af[i], bfr[j], acc[i][j], 0, 0, 0);
    }
}

// Fused QKV projection. grid (24, 64).
__global__ __launch_bounds__(256) void qkv_gemm_kernel(const __bf16* __restrict__ A,
                                                       const __bf16* __restrict__ Wq,
                                                       const __bf16* __restrict__ Wk,
                                                       const __bf16* __restrict__ Wv,
                                                       __hip_bfloat16* __restrict__ Q,
                                                       __hip_bfloat16* __restrict__ Kd,
                                                       __hip_bfloat16* __restrict__ VT)
{
    __shared__ __align__(16) __bf16 As[128 * 32];
    __shared__ __align__(16) __bf16 Bs[128 * 32];

    const int nt  = blockIdx.x;
    const int mt  = blockIdx.y;
    const int mat = nt >> 3;
    const int n0  = (nt & 7) * 128;
    const int m0  = mt * 128;
    const __bf16* W = (mat == 0) ? Wq : (mat == 1) ? Wk : Wv;

    floatx4 acc[4][4] = {};
    gemm_mainloop(A, W, m0, n0, As, Bs, acc);

    const int wv_  = threadIdx.x >> 6;
    const int lane = threadIdx.x & 63;
    const int l16  = lane & 15;
    const int quad = lane >> 4;
    const int mi0  = (wv_ >> 1) * 64;
    const int ni0  = (wv_ & 1) * 64;

    if (mat < 2) {
        __hip_bfloat16* dst = (mat == 0) ? Q : Kd;
        #pragma unroll
        for (int i = 0; i < 4; ++i) {
            #pragma unroll
            for (int j = 0; j < 4; ++j) {
                const int col = n0 + ni0 + j * 16 + l16;
                const int h = col >> 6, d = col & 63;
                #pragma unroll
                for (int r = 0; r < 4; ++r) {
                    const int row = m0 + mi0 + i * 16 + quad * 4 + r;
                    const int b = row >> 11, t = row & (T_SEQ - 1);
                    dst[(((size_t)(b * NH + h)) * T_SEQ + t) * DK + d] = __float2bfloat16(acc[i][j][r]);
                }
            }
        }
    } else {
        #pragma unroll
        for (int i = 0; i < 4; ++i) {
            const int row0 = m0 + mi0 + i * 16 + quad * 4;
            const int b = row0 >> 11, t0 = row0 & (T_SEQ - 1);
            #pragma unroll
            for (int j = 0; j < 4; ++j) {
                const int col = n0 + ni0 + j * 16 + l16;
                const int h = col >> 6, d = col & 63;
                bf16x4 e;
                #pragma unroll
                for (int r = 0; r < 4; ++r) e[r] = (__bf16)acc[i][j][r];
                *(bf16x4*)&VT[(((size_t)(b * NH + h)) * DK + d) * T_SEQ + t0] = e;
            }
        }
    }
}

// O projection -> fp32 d_out. grid (8, 64).
__global__ __launch_bounds__(256) void oproj_gemm_kernel(const __bf16* __restrict__ A,
                                                         const __bf16* __restrict__ W,
                                                         float* __restrict__ out)
{
    __shared__ __align__(16) __bf16 As[128 * 32];
    __shared__ __align__(16) __bf16 Bs[128 * 32];

    const int n0 = blockIdx.x * 128;
    const int m0 = blockIdx.y * 128;

    floatx4 acc[4][4] = {};
    gemm_mainloop(A, W, m0, n0, As, Bs, acc);

    const int wv_  = threadIdx.x >> 6;
    const int lane = threadIdx.x & 63;
    const int l16  = lane & 15;
    const int quad = lane >> 4;
    const int mi0  = (wv_ >> 1) * 64;
    const int ni0  = (wv_ & 1) * 64;

    #pragma unroll
    for (int i = 0; i < 4; ++i) {
        #pragma unroll
        for (int j = 0; j < 4; ++j) {
            const int col = n0 + ni0 + j * 16 + l16;
            #pragma unroll
            for (int r = 0; r < 4; ++r) {
                const int row = m0 + mi0 + i * 16 + quad * 4 + r;
                out[(size_t)row * DM + col] = acc[i][j][r];
            }
        }
    }
}

// In-place RoPE on Q and K. Q additionally scaled by (1/8)*log2(e) so the
// attention softmax can run natively in exp2 domain (v_exp_f32).
__global__ __launch_bounds__(256) void rope_kernel(__hip_bfloat16* __restrict__ Q,
                                                   __hip_bfloat16* __restrict__ K,
                                                   const int* __restrict__ tp)
{
    const int idx = blockIdx.x * 256 + threadIdx.x;
    const int f = idx & 31;
    const int t = (idx >> 5) & (T_SEQ - 1);
    const int h = (idx >> 16) & (NH - 1);
    const int b = idx >> 20;

    const int pos = tp[b * T_SEQ + t];
    const float inv = exp2f(-(float)f * 0.41524101186092029f);
    const float ang = (float)pos * inv;
    float s, c;
    sincosf(ang, &s, &c);

    const float QS = 0.18033688011112043f;   // 0.125 * log2(e)
    const size_t off = (((size_t)(b * NH + h)) * T_SEQ + t) * DK + 2 * f;
    const float q0 = __bfloat162float(Q[off]);
    const float q1 = __bfloat162float(Q[off + 1]);
    Q[off]     = __float2bfloat16((q0 * c - q1 * s) * QS);
    Q[off + 1] = __float2bfloat16((q1 * c + q0 * s) * QS);
    const float k0 = __bfloat162float(K[off]);
    const float k1 = __bfloat162float(K[off + 1]);
    K[off]     = __float2bfloat16(k0 * c - k1 * s);
    K[off + 1] = __float2bfloat16(k1 * c + k0 * s);
}

// ---------------------------------------------------------------------------
// Flash attention v4: round-7 structure (independent waves, bh in LOW blockIdx
// bits for XCD/L2 affinity, longest-first) with KV chunk = 64 (half the
// softmax rounds / shfls / LDS round-trips per col) and exp2-domain softmax.
// ---------------------------------------------------------------------------
__global__ __launch_bounds__(256) void fattn_kernel(const __bf16* __restrict__ Q,
                                                    const __bf16* __restrict__ K,
                                                    const __bf16* __restrict__ VT,
                                                    __hip_bfloat16* __restrict__ AO)
{
    __shared__ __align__(16) __hip_bfloat16 sh_p[4][16][72];  // stride 72: 2-way = free

    const int wv   = threadIdx.x >> 6;
    const int lane = threadIdx.x & 63;
    const int l16  = lane & 15;
    const int quad = lane >> 4;

    const int bk = blockIdx.x;                  // 2048 blocks
    const int ig = bk >> 6;                     // 0..31, longest-first
    const int bh = bk & 63;                     // low bits -> same-XCD per head
    const int tile = 127 - (ig * 4 + wv);
    const int b = bh >> 4, h = bh & (NH - 1);
    const int qi0 = tile * 16;
    const int qi  = qi0 + l16;                  // this lane's Q-row

    const __bf16* Qp = Q + ((size_t)bh * T_SEQ + qi0 + l16) * DK + quad * 8;
    const bf16x8 qb0 = *(const bf16x8*)Qp;
    const bf16x8 qb1 = *(const bf16x8*)(Qp + 32);

    const __bf16* Kb = K  + (size_t)bh * T_SEQ * DK;
    const __bf16* Vb = VT + (size_t)bh * DK * T_SEQ;

    floatx4 o0 = {0,0,0,0}, o1 = {0,0,0,0}, o2 = {0,0,0,0}, o3 = {0,0,0,0};
    float m_run = -1e30f;
    float l_run = 0.f;

    const int nch   = (qi0 + 79) >> 6;          // 64-wide KV chunks (cols to qi0+15)
    const int nfull = (qi0 + 1) >> 6;           // chunks needing no mask

    for (int c = 0; c < nch; ++c) {
        const int tj0 = c * 64;

        // QK^T: 4 S-tiles (16 KV rows each), K rows are A-operand
        const __bf16* kp = Kb + (size_t)(tj0 + l16) * DK + quad * 8;
        floatx4 s[4] = {{0,0,0,0},{0,0,0,0},{0,0,0,0},{0,0,0,0}};
        #pragma unroll
        for (int g = 0; g < 4; ++g) {
            const bf16x8 kl = *(const bf16x8*)(kp + g * 16 * DK);
            const bf16x8 kh = *(const bf16x8*)(kp + g * 16 * DK + 32);
            s[g] = __builtin_amdgcn_mfma_f32_16x16x32_bf16(kl, qb0, s[g], 0, 0, 0);
            s[g] = __builtin_amdgcn_mfma_f32_16x16x32_bf16(kh, qb1, s[g], 0, 0, 0);
        }

        // causal mask (only the boundary chunk needs it)
        if (c >= nfull) {
            #pragma unroll
            for (int g = 0; g < 4; ++g)
                #pragma unroll
                for (int r = 0; r < 4; ++r)
                    if (tj0 + 16 * g + quad * 4 + r > qi) s[g][r] = -1e30f;
        }

        // per-lane online softmax (lane l16 = Q-row), exp2 domain
        float mloc = -1e30f;
        #pragma unroll
        for (int g = 0; g < 4; ++g)
            #pragma unroll
            for (int r = 0; r < 4; ++r)
                mloc = fmaxf(mloc, s[g][r]);
        mloc = fmaxf(mloc, __shfl_xor(mloc, 16));
        mloc = fmaxf(mloc, __shfl_xor(mloc, 32));
        const float nm = fmaxf(m_run, mloc);
        const float al = exp2f(m_run - nm);
        m_run = nm;

        float ls = 0.f;
        #pragma unroll
        for (int g = 0; g < 4; ++g) {
            bf16x4 w;
            #pragma unroll
            for (int r = 0; r < 4; ++r) {
                const float p = exp2f(s[g][r] - nm);
                ls += p;
                w[r] = (__bf16)p;
            }
            *(bf16x4*)&sh_p[wv][l16][16 * g + quad * 4] = w;   // P^T[qrow][kvcol]
        }
        ls += __shfl_xor(ls, 16);
        ls += __shfl_xor(ls, 32);
        l_run = l_run * al + ls;

        #pragma unroll
        for (int r = 0; r < 4; ++r) {
            o0[r] *= al; o1[r] *= al; o2[r] *= al; o3[r] *= al;
        }

        asm volatile("s_waitcnt lgkmcnt(0)" ::: "memory");
        __builtin_amdgcn_wave_barrier();

        // PV in two 32-wide k-halves; V^T rows are A-operand, P is B-operand
        #pragma unroll
        for (int h2 = 0; h2 < 2; ++h2) {
            const bf16x8 pb = *(const bf16x8*)&sh_p[wv][l16][h2 * 32 + quad * 8];
            const __bf16* vp = Vb + (size_t)l16 * T_SEQ + tj0 + h2 * 32 + quad * 8;
            o0 = __builtin_amdgcn_mfma_f32_16x16x32_bf16(*(const bf16x8*)(vp),               pb, o0, 0, 0, 0);
            o1 = __builtin_amdgcn_mfma_f32_16x16x32_bf16(*(const bf16x8*)(vp + 16 * T_SEQ), pb, o1, 0, 0, 0);
            o2 = __builtin_amdgcn_mfma_f32_16x16x32_bf16(*(const bf16x8*)(vp + 32 * T_SEQ), pb, o2, 0, 0, 0);
            o3 = __builtin_amdgcn_mfma_f32_16x16x32_bf16(*(const bf16x8*)(vp + 48 * T_SEQ), pb, o3, 0, 0, 0);
        }
        __builtin_amdgcn_wave_barrier();
    }

    const float inv = 1.0f / l_run;
    __hip_bfloat16* Ao = AO + ((size_t)b * T_SEQ + qi0 + l16) * DM + h * 64 + quad * 4;
    bf16x4 e;
    #pragma unroll
    for (int r = 0; r < 4; ++r) e[r] = (__bf16)(o0[r] * inv);
    *(bf16x4*)(Ao +  0) = e;
    #pragma unroll
    for (int r = 0; r < 4; ++r) e[r] = (__bf16)(o1[r] * inv);
    *(bf16x4*)(Ao + 16) = e;
    #pragma unroll
    for (int r = 0; r < 4; ++r) e[r] = (__bf16)(o2[r] * inv);
    *(bf16x4*)(Ao + 32) = e;
    #pragma unroll
    for (int r = 0; r < 4; ++r) e[r] = (__bf16)(o3[r] * inv);
    *(bf16x4*)(Ao + 48) = e;
}

extern "C" void kernel_launch(void* const* d_in, const int* in_sizes, int n_in,
                              void* d_out, int out_size, void* d_ws, size_t ws_size,
                              hipStream_t stream) {
    const float* x  = (const float*)d_in[0];
    const int*   tp = (const int*)d_in[1];
    const float* wq = (const float*)d_in[2];
    const float* wk = (const float*)d_in[3];
    const float* wv = (const float*)d_in[4];
    const float* wo = (const float*)d_in[5];

    char* ws = (char*)d_ws;
    const size_t XSZ = (size_t)B_SZ * T_SEQ * DM * 2;       // 16.78 MB
    const size_t WSZ = (size_t)DM * DM * 2;                 // 2 MB
    const size_t SZ  = (size_t)B_SZ * NH * T_SEQ * DK * 2;  // 16.78 MB

    __hip_bfloat16* xb  = (__hip_bfloat16*)(ws);
    __hip_bfloat16* wqb = (__hip_bfloat16*)(ws + XSZ);       // wq..wo contiguous
    __hip_bfloat16* wkb = (__hip_bfloat16*)(ws + XSZ + WSZ);
    __hip_bfloat16* wvb = (__hip_bfloat16*)(ws + XSZ + 2 * WSZ);
    __hip_bfloat16* wob = (__hip_bfloat16*)(ws + XSZ + 3 * WSZ);
    __hip_bfloat16* Q   = (__hip_bfloat16*)(ws + XSZ + 4 * WSZ);
    __hip_bfloat16* K   = (__hip_bfloat16*)(ws + XSZ + 4 * WSZ + SZ);
    __hip_bfloat16* VT  = (__hip_bfloat16*)(ws + XSZ + 4 * WSZ + 2 * SZ);
    __hip_bfloat16* AO  = (__hip_bfloat16*)(ws + XSZ + 4 * WSZ + 3 * SZ);
    float* out = (float*)d_out;

    // 1. canonicalize fp32 inputs to bf16 (x + all four weights)
    convert4_kernel<<<8192, 256, 0, stream>>>(x, xb, B_SZ * T_SEQ * DM / 4);
    convertw_kernel<<<4096, 256, 0, stream>>>(wq, wk, wv, wo, wqb);

    // 2. fused QKV projection: Q,K -> [bh][t][64]; V -> [bh][64][t]
    qkv_gemm_kernel<<<dim3(24, 64), 256, 0, stream>>>(
        (const __bf16*)xb, (const __bf16*)wqb, (const __bf16*)wkb, (const __bf16*)wvb,
        Q, K, VT);

    // 3. RoPE in place on Q (scaled by 0.125*log2e), K
    rope_kernel<<<16384, 256, 0, stream>>>(Q, K, tp);

    // 4. flash attention -> AO [B][T][DM] (bf16)
    fattn_kernel<<<2048, 256, 0, stream>>>((const __bf16*)Q, (const __bf16*)K,
                                           (const __bf16*)VT, AO);

    // 5. O projection -> d_out (fp32)
    oproj_gemm_kernel<<<dim3(8, 64), 256, 0, stream>>>(
        (const __bf16*)AO, (const __bf16*)wob, out);
}